// Round 7
// baseline (218.583 us; speedup 1.0000x reference)
//
#include <hip/hip_runtime.h>

// inputs: (B=8, C=2, D=96, H=64, W=64) f32
// weight/bias: (F=8, C=2, d=3, h=60, w=64) f32
// out: (B=8, F=8, Dout=94, h=60, w=64) f32
#define B_ 8
#define C_ 2
#define D_ 96
#define H_ 64
#define W_ 64
#define F_ 8
#define KD 3
#define h_ 60
#define Dout_ 94
#define PLANE (h_ * W_)          // 3840 floats
#define NCH (PLANE / 4)          // 960 float4 per plane
#define NS2 (B_ * C_ * D_)       // 1536 s2 planes
#define S2_FLOATS ((size_t)NS2 * PLANE)
#define NDT (Dout_ / 2)          // 47 dout-pairs (94 = 2*47, no tail)
#define FT 4                     // f per k_main block
#define NFG (F_ / FT)            // 2

__device__ __forceinline__ float4 f4fma(float4 a, float4 b, float4 c) {
    c.x += a.x * b.x; c.y += a.y * b.y; c.z += a.z * b.z; c.w += a.w * b.w;
    return c;
}
__device__ __forceinline__ float4 f4add3(float4 a, float4 b, float4 c) {
    float4 o;
    o.x = a.x + b.x + c.x; o.y = a.y + b.y + c.y;
    o.z = a.z + b.z + c.z; o.w = a.w + b.w + c.w;
    return o;
}

// Horizontal 3-tap sum via lane shuffles; c4 = float4-column 0..15 within a
// 16-lane row group. Boundary columns contribute zero. Call from ALL lanes.
__device__ __forceinline__ float4 hsum3(float4 V, int c4) {
    const int lane = threadIdx.x & 63;
    float lw = __shfl(V.w, (lane + 63) & 63, 64);
    float rx = __shfl(V.x, (lane + 1) & 63, 64);
    if (c4 == 0) lw = 0.f;
    if (c4 == 15) rx = 0.f;
    float4 o;
    o.x = lw + V.x + V.y;
    o.y = V.x + V.y + V.z;
    o.z = V.y + V.z + V.w;
    o.w = V.z + V.w + rx;
    return o;
}

// ---------------------------------------------------------------------------
// Prep kernel (proven):
// Blocks 0..NS2-1:       S2[b,c,p] = vertical 5-sum of input plane.
// Blocks NS2..NS2+F_-1:  bb[f]     = Box3x3( sum_{c,z} bias[f,c,z] ).
// ---------------------------------------------------------------------------
__global__ __launch_bounds__(256) void k_prep(const float* __restrict__ in,
                                              const float* __restrict__ bs,
                                              float* __restrict__ s2,
                                              float* __restrict__ bb) {
    const int bx = blockIdx.x;
    const int tid = threadIdx.x;
    __shared__ float4 lds[H_ * 16];  // 16 KB

    if (bx < NS2) {
        const float4* ip4 = (const float4*)(in + (size_t)bx * (H_ * W_));
        float4* op4 = (float4*)(s2 + (size_t)bx * PLANE);
#pragma unroll
        for (int k = 0; k < 4; ++k) lds[tid + 256 * k] = ip4[tid + 256 * k];
        __syncthreads();
#pragma unroll
        for (int k = 0; k < 4; ++k) {
            const int e = tid + 256 * k;
            if (e < NCH) {
                const int row = e >> 4, col = e & 15;
                float4 s = lds[row * 16 + col];
#pragma unroll
                for (int j = 1; j < 5; ++j) {
                    const float4 v = lds[(row + j) * 16 + col];
                    s.x += v.x; s.y += v.y; s.z += v.z; s.w += v.w;
                }
                op4[e] = s;
            }
        }
    } else {
        const int f = bx - NS2;
        float4* R = lds;  // rows 0..61, rows 0 and 61 zeroed
        if (tid < 32) {
            const int r = (tid >> 4) ? 61 : 0;
            R[r * 16 + (tid & 15)] = make_float4(0, 0, 0, 0);
        }
        const float4* bp = (const float4*)(bs + (size_t)f * (C_ * KD * PLANE));
#pragma unroll
        for (int k = 0; k < 4; ++k) {
            const int e = tid + 256 * k;
            if (e < NCH) {
                float4 s = make_float4(0, 0, 0, 0);
#pragma unroll
                for (int s6 = 0; s6 < 6; ++s6) {
                    const float4 v = bp[s6 * NCH + e];
                    s.x += v.x; s.y += v.y; s.z += v.z; s.w += v.w;
                }
                R[((e >> 4) + 1) * 16 + (e & 15)] = s;
            }
        }
        __syncthreads();
        float4* ob = (float4*)(bb + (size_t)f * PLANE);
#pragma unroll
        for (int k = 0; k < 4; ++k) {
            const int e = tid + 256 * k;
            int c4 = e & 15;
            float4 V = make_float4(0, 0, 0, 0);
            if (e < NCH) {
                const int row = e >> 4;
                V = f4add3(R[row * 16 + c4], R[(row + 1) * 16 + c4],
                           R[(row + 2) * 16 + c4]);
            }
            float4 o = hsum3(V, c4);
            if (e < NCH) ob[e] = o;
        }
    }
}

// ---------------------------------------------------------------------------
// Main kernel. Block = (b, dout-pair, f-quad); 512 threads; 752 blocks.
// S2 slice-windows (2c x 4z = 8 slices, 2 chunks/thread) pinned in 64 VGPRs,
// read ONCE per block. f-loop (unroll 1): 12 weight chunks streamed from
// L2-resident weights, shared across both douts; acc produced AND consumed
// in the same iteration (nothing for the compiler to sink). Box per plane:
// t-indexed ping-pong LDS, 1 barrier/plane, full contiguous plane stores.
// ---------------------------------------------------------------------------
__global__ __launch_bounds__(512) void k_main(const float* __restrict__ s2,
                                              const float* __restrict__ wt,
                                              const float* __restrict__ bb,
                                              float* __restrict__ out) {
    const int bx = blockIdx.x;
    const int fg = bx & 1;
    const int dt = (bx >> 1) % NDT;
    const int b  = bx / (2 * NDT);
    const int d0 = dt * 2;
    const int f0 = fg * FT;
    const int tid = threadIdx.x;

    __shared__ float4 Lb2[2][62 * 16];   // 31,744 B ping-pong box buffers

    const float4 z4 = make_float4(0, 0, 0, 0);

    int e[2], c4[2], row[2];
    bool act[2];
#pragma unroll
    for (int k = 0; k < 2; ++k) {
        e[k] = tid + 512 * k;        // 0..1023
        row[k] = e[k] >> 4;          // 0..63
        c4[k] = e[k] & 15;
        act[k] = (e[k] < NCH);       // e < 960 -> box rows 1..60
    }

    // Zero halo rows (0 and 61) of both buffers; visible after first barrier.
    if (tid < 64) {
        const int buf = tid >> 5, idx = tid & 31;
        const int r = (idx >> 4) ? 61 : 0;
        Lb2[buf][r * 16 + (idx & 15)] = z4;
    }

    // ---- S2 windows into registers (read once) ----
    float4 s2r[C_][4][2];            // [c][z-window 0..3][chunk]
    const float4* s2f = (const float4*)s2;
#pragma unroll
    for (int c = 0; c < C_; ++c)
#pragma unroll
        for (int zz = 0; zz < 4; ++zz) {
            const float4* sp = s2f + (size_t)((b * C_ + c) * D_ + d0 + zz) * NCH;
#pragma unroll
            for (int k = 0; k < 2; ++k)
                s2r[c][zz][k] = act[k] ? sp[e[k]] : z4;
        }

    const float4* wt4 = (const float4*)wt;
    const float4* bb4 = (const float4*)bb;
    float4* out4 = (float4*)out;

#pragma unroll 1
    for (int fi = 0; fi < FT; ++fi) {
        const int f = f0 + fi;

        float4 acc[2][2];            // [t=dout within pair][chunk]
#pragma unroll
        for (int t = 0; t < 2; ++t)
#pragma unroll
            for (int k = 0; k < 2; ++k) acc[t][k] = z4;

#pragma unroll
        for (int c = 0; c < C_; ++c)
#pragma unroll
            for (int z = 0; z < KD; ++z) {
                const float4* wp = wt4 + (size_t)((f * C_ + c) * KD + z) * NCH;
                float4 w[2];
#pragma unroll
                for (int k = 0; k < 2; ++k) w[k] = act[k] ? wp[e[k]] : z4;
#pragma unroll
                for (int k = 0; k < 2; ++k) {
                    acc[0][k] = f4fma(w[k], s2r[c][z][k], acc[0][k]);
                    acc[1][k] = f4fma(w[k], s2r[c][z + 1][k], acc[1][k]);
                }
            }

        float4 bbv[2];
#pragma unroll
        for (int k = 0; k < 2; ++k)
            bbv[k] = act[k] ? bb4[(size_t)f * NCH + e[k]] : z4;

#pragma unroll
        for (int t = 0; t < 2; ++t) {
            float4* Lb = Lb2[t];     // ping-pong by t (phases alternate t)
#pragma unroll
            for (int k = 0; k < 2; ++k)
                if (act[k]) Lb[(row[k] + 1) * 16 + c4[k]] = acc[t][k];
            __syncthreads();         // one barrier per output plane

            const size_t ob = (size_t)((b * F_ + f) * Dout_ + d0 + t) * NCH;
#pragma unroll
            for (int k = 0; k < 2; ++k) {
                float4 V = z4;
                if (act[k])
                    V = f4add3(Lb[row[k] * 16 + c4[k]],
                               Lb[(row[k] + 1) * 16 + c4[k]],
                               Lb[(row[k] + 2) * 16 + c4[k]]);
                float4 o = hsum3(V, c4[k]);   // uniform: no shuffle divergence
                if (act[k]) {
                    o.x = 0.25f * (o.x + bbv[k].x);
                    o.y = 0.25f * (o.y + bbv[k].y);
                    o.z = 0.25f * (o.z + bbv[k].z);
                    o.w = 0.25f * (o.w + bbv[k].w);
                    o.x = (o.x > 0.f) ? o.x : 0.2f * o.x;
                    o.y = (o.y > 0.f) ? o.y : 0.2f * o.y;
                    o.z = (o.z > 0.f) ? o.z : 0.2f * o.z;
                    o.w = (o.w > 0.f) ? o.w : 0.2f * o.w;
                    out4[ob + e[k]] = o;
                }
            }
        }
    }
}

extern "C" void kernel_launch(void* const* d_in, const int* in_sizes, int n_in,
                              void* d_out, int out_size, void* d_ws, size_t ws_size,
                              hipStream_t stream) {
    const float* in = (const float*)d_in[0];
    const float* wt = (const float*)d_in[1];
    const float* bs = (const float*)d_in[2];
    float* out = (float*)d_out;

    float* s2 = (float*)d_ws;        // 23.6 MB
    float* bb = s2 + S2_FLOATS;      // +123 KB

    k_prep<<<dim3(NS2 + F_), dim3(256), 0, stream>>>(in, bs, s2, bb);
    // grid: b(8) x dout-pair(47) x f-quad(2) = 752 blocks
    k_main<<<dim3(B_ * NDT * NFG), dim3(512), 0, stream>>>(s2, wt, bb, out);
}